// Round 2
// baseline (83.524 us; speedup 1.0000x reference)
//
#include <hip/hip_runtime.h>

#define LEAKY_S 0.01f
#define BN_EPS 1e-5f
#define LOG2E 1.44269504088896340736f

__device__ __forceinline__ float leaky(float v) { return v >= 0.0f ? v : LEAKY_S * v; }

#if __has_builtin(__builtin_amdgcn_exp2f)
__device__ __forceinline__ float fast_exp2(float v) { return __builtin_amdgcn_exp2f(v); }
#else
__device__ __forceinline__ float fast_exp2(float v) { return exp2f(v); }
#endif

// sigmoid(z) with pre-scaled (log2e) weights: z2 = z*log2e already
__device__ __forceinline__ float sig2(float z2) {
    return __builtin_amdgcn_rcpf(1.0f + fast_exp2(-z2));
}

// ---------------- K1: partial sums (sum, sumsq) of h1 columns over batch ----
__global__ __launch_bounds__(256) void k_part1(const float* __restrict__ x,
        const float* __restrict__ w1, const float* __restrict__ b1,
        float* __restrict__ p1, int B) {
    float w1r[16], b1r[16], s[16], q[16];
#pragma unroll
    for (int j = 0; j < 16; ++j) { w1r[j] = w1[j]; b1r[j] = b1[j]; s[j] = 0.f; q[j] = 0.f; }
    int tid = threadIdx.x;
    int stride = gridDim.x * 256;
    for (int i = blockIdx.x * 256 + tid; i < B; i += stride) {
        float xv = x[i];
#pragma unroll
        for (int j = 0; j < 16; ++j) {
            float h = leaky(fmaf(xv, w1r[j], b1r[j]));
            s[j] += h; q[j] += h * h;
        }
    }
#pragma unroll
    for (int j = 0; j < 16; ++j) {
        for (int off = 32; off >= 1; off >>= 1) {
            s[j] += __shfl_xor(s[j], off, 64);
            q[j] += __shfl_xor(q[j], off, 64);
        }
    }
    __shared__ float red[4][32];
    int w = tid >> 6, lane = tid & 63;
    if (lane == 0) {
#pragma unroll
        for (int j = 0; j < 16; ++j) { red[w][j] = s[j]; red[w][j + 16] = q[j]; }
    }
    __syncthreads();
    if (tid < 32)
        p1[blockIdx.x * 32 + tid] = red[0][tid] + red[1][tid] + red[2][tid] + red[3][tid];
}

// Wave0 helper: fold BN1 + Linear2 into coef[0..15]=a[j], coef[16]=c0.
// Executed by lanes 0..31 (p1 has 64 blocks x 32 cols).
__device__ __forceinline__ void fold_bn1(const float* __restrict__ p1,
        const float* __restrict__ w2, const float* __restrict__ b2,
        const float* __restrict__ g1, const float* __restrict__ be1,
        float* coef, int tid, float invB) {
    float acc = 0.f;
    for (int i = 0; i < 64; ++i) acc += p1[i * 32 + tid];
    float qacc = __shfl(acc, tid + 16, 64);   // lanes 0..15 fetch sumsq
    float cp = 0.f;
    if (tid < 16) {
        float mean = acc * invB;
        float var  = qacc * invB - mean * mean;
        float inv  = rsqrtf(var + BN_EPS) * g1[tid];
        float sh   = fmaf(-mean, inv, be1[tid]);
        coef[tid] = inv * w2[tid];
        cp = sh * w2[tid];
    }
    for (int off = 8; off >= 1; off >>= 1) cp += __shfl_xor(cp, off, 16);
    if (tid == 0) coef[16] = cp + b2[0];
}

// ---------------- K2: h2 per row + partial (sum,sumsq) for BN2 (fin1 inline)
__global__ __launch_bounds__(256) void k_h2f(const float* __restrict__ x,
        const float* __restrict__ w1, const float* __restrict__ b1,
        const float* __restrict__ p1, const float* __restrict__ w2,
        const float* __restrict__ b2, const float* __restrict__ g1,
        const float* __restrict__ be1, float* __restrict__ p2, int B, float invB) {
    __shared__ float coef[17];
    int tid = threadIdx.x;
    if (tid < 32) fold_bn1(p1, w2, b2, g1, be1, coef, tid, invB);
    __syncthreads();
    float w1r[16], b1r[16], ar[16];
#pragma unroll
    for (int j = 0; j < 16; ++j) { w1r[j] = w1[j]; b1r[j] = b1[j]; ar[j] = coef[j]; }
    float c0 = coef[16];
    float s = 0.f, q = 0.f;
    int stride = gridDim.x * 256;
    for (int i = blockIdx.x * 256 + tid; i < B; i += stride) {
        float xv = x[i];
        float acc = c0;
#pragma unroll
        for (int j = 0; j < 16; ++j) {
            float h = leaky(fmaf(xv, w1r[j], b1r[j]));
            acc = fmaf(h, ar[j], acc);
        }
        float h2 = leaky(acc);
        s += h2; q += h2 * h2;
    }
    for (int off = 32; off >= 1; off >>= 1) {
        s += __shfl_xor(s, off, 64);
        q += __shfl_xor(q, off, 64);
    }
    __shared__ float red[4][2];
    int w = tid >> 6, lane = tid & 63;
    if (lane == 0) { red[w][0] = s; red[w][1] = q; }
    __syncthreads();
    if (tid == 0) {
        p2[blockIdx.x * 2 + 0] = red[0][0] + red[1][0] + red[2][0] + red[3][0];
        p2[blockIdx.x * 2 + 1] = red[0][1] + red[1][1] + red[2][1] + red[3][1];
    }
}

// ---------------- K3: register-resident tree. 1 wave = 4 rows, no barriers
// in the main computation. Contiguous-block node->lane layout keeps levels
// 7..10 entirely in-lane; levels 1..6 use one shfl pair per level.
__global__ __launch_bounds__(256) void k_tree(const float* __restrict__ x,
        const float* __restrict__ w1, const float* __restrict__ b1,
        const float* __restrict__ w2, const float* __restrict__ b2,
        const float* __restrict__ g1, const float* __restrict__ be1,
        const float* __restrict__ g2, const float* __restrict__ be2,
        const float* __restrict__ fcw, const float* __restrict__ fcb,
        const float* __restrict__ p1, const float* __restrict__ p2,
        float* __restrict__ out, int B, float invB) {
    __shared__ float wl[1024], bl[1024];
    __shared__ float coef[19];
    __shared__ float x2s[16];
    int tid = threadIdx.x;

    // Stage fc weights: pre-scaled by log2e, slot-major swizzle per level
    // segment so all per-level LDS reads are stride-1 (conflict-free).
    for (int i = tid; i < 1024; i += 256) {
        int d;
        if (i < 128)      d = i;                                            // levels 1..7
        else if (i < 256) { int o = i - 128; d = 128 + ((o & 1) << 6) + (o >> 1); } // l8
        else if (i < 512) { int o = i - 256; d = 256 + ((o & 3) << 6) + (o >> 2); } // l9
        else              { int o = i - 512; d = 512 + ((o & 7) << 6) + (o >> 3); } // l10
        wl[d] = fcw[i] * LOG2E;
        bl[d] = fcb[i] * LOG2E;
    }
    if (tid < 32) {
        fold_bn1(p1, w2, b2, g1, be1, coef, tid, invB);
        if (tid == 31) {   // BN2 fold -> s2 (coef[17]), t2 (coef[18])
            float s = 0.f, q = 0.f;
            for (int i = 0; i < 64; ++i) { s += p2[2 * i]; q += p2[2 * i + 1]; }
            float mean = s * invB, var = q * invB - mean * mean;
            float inv = rsqrtf(var + BN_EPS) * g2[0];
            coef[17] = inv;
            coef[18] = fmaf(-mean, inv, be2[0]);
        }
    }
    __syncthreads();
    // One thread per block-row: recompute h2 -> x2 (16 rows/block)
    if (tid < 16) {
        int r = blockIdx.x * 16 + tid;
        float xv = (r < B) ? x[r] : 0.f;
        float acc = coef[16];
#pragma unroll
        for (int j = 0; j < 16; ++j) {
            float h = leaky(fmaf(xv, w1[j], b1[j]));
            acc = fmaf(h, coef[j], acc);
        }
        x2s[tid] = fmaf(leaky(acc), coef[17], coef[18]);
    }
    __syncthreads();

    const int w = tid >> 6, lane = tid & 63;
    const int rbase = blockIdx.x * 16 + w * 4;
    float x2[4]; bool act[4]; float* op[4];
#pragma unroll
    for (int rr = 0; rr < 4; ++rr) {
        x2[rr] = x2s[w * 4 + rr];
        act[rr] = (rbase + rr) < B;
        op[rr] = out + (size_t)(rbase + rr) * 2048;
        if (act[rr] && lane == 0)
            *reinterpret_cast<float2*>(op[rr]) = make_float2(0.f, 1.f);
    }

    float mup[4] = {1.f, 1.f, 1.f, 1.f};
    // ---- levels 1..6: shuffle levels (P = 1..32 parents) ----
#pragma unroll
    for (int l = 1; l <= 6; ++l) {
        const int P = 1 << (l - 1);
        float wv = wl[P + lane], bv = bl[P + lane];
#pragma unroll
        for (int rr = 0; rr < 4; ++rr) {
            float z = fmaf(x2[rr], wv, bv);
            float pz = sig2(z);
            float c0 = mup[rr] * pz, c1 = mup[rr] - c0;
            if (act[rr] && lane < P)
                *reinterpret_cast<float2*>(op[rr] + 2 * (P + lane)) = make_float2(c0, c1);
            float s0 = __shfl(c0, lane >> 1, 64);
            float s1 = __shfl(c1, lane >> 1, 64);
            mup[rr] = (lane & 1) ? s1 : s0;
        }
    }
    // ---- level 7: P=64, one parent/lane; children stay in-lane ----
    float c2[4][2];
    {
        float wv = wl[64 + lane], bv = bl[64 + lane];
#pragma unroll
        for (int rr = 0; rr < 4; ++rr) {
            float z = fmaf(x2[rr], wv, bv);
            float pz = sig2(z);
            c2[rr][0] = mup[rr] * pz;
            c2[rr][1] = mup[rr] - c2[rr][0];
            if (act[rr])
                *reinterpret_cast<float2*>(op[rr] + 128 + 2 * lane) =
                    make_float2(c2[rr][0], c2[rr][1]);
        }
    }
    // ---- level 8: 2 parents/lane ----
    float c4[4][4];
#pragma unroll
    for (int s = 0; s < 2; ++s) {
        float wv = wl[128 + (s << 6) + lane], bv = bl[128 + (s << 6) + lane];
#pragma unroll
        for (int rr = 0; rr < 4; ++rr) {
            float z = fmaf(x2[rr], wv, bv);
            float pz = sig2(z);
            c4[rr][2 * s]     = c2[rr][s] * pz;
            c4[rr][2 * s + 1] = c2[rr][s] - c4[rr][2 * s];
        }
    }
#pragma unroll
    for (int rr = 0; rr < 4; ++rr)
        if (act[rr])
            *reinterpret_cast<float4*>(op[rr] + 256 + 4 * lane) =
                make_float4(c4[rr][0], c4[rr][1], c4[rr][2], c4[rr][3]);
    // ---- level 9: 4 parents/lane ----
    float c8[4][8];
#pragma unroll
    for (int s = 0; s < 4; ++s) {
        float wv = wl[256 + (s << 6) + lane], bv = bl[256 + (s << 6) + lane];
#pragma unroll
        for (int rr = 0; rr < 4; ++rr) {
            float z = fmaf(x2[rr], wv, bv);
            float pz = sig2(z);
            c8[rr][2 * s]     = c4[rr][s] * pz;
            c8[rr][2 * s + 1] = c4[rr][s] - c8[rr][2 * s];
        }
    }
#pragma unroll
    for (int rr = 0; rr < 4; ++rr) {
        if (act[rr]) {
            *reinterpret_cast<float4*>(op[rr] + 512 + 8 * lane) =
                make_float4(c8[rr][0], c8[rr][1], c8[rr][2], c8[rr][3]);
            *reinterpret_cast<float4*>(op[rr] + 512 + 8 * lane + 4) =
                make_float4(c8[rr][4], c8[rr][5], c8[rr][6], c8[rr][7]);
        }
    }
    // ---- level 10: 8 parents/lane, write 16 floats/lane/row ----
#pragma unroll
    for (int s = 0; s < 8; s += 2) {
        float wv0 = wl[512 + (s << 6) + lane],       bv0 = bl[512 + (s << 6) + lane];
        float wv1 = wl[512 + ((s + 1) << 6) + lane], bv1 = bl[512 + ((s + 1) << 6) + lane];
#pragma unroll
        for (int rr = 0; rr < 4; ++rr) {
            float z0 = fmaf(x2[rr], wv0, bv0);
            float z1 = fmaf(x2[rr], wv1, bv1);
            float p0 = sig2(z0), p1v = sig2(z1);
            float a0 = c8[rr][s] * p0,     a1 = c8[rr][s] - a0;
            float b0 = c8[rr][s + 1] * p1v, b1 = c8[rr][s + 1] - b0;
            if (act[rr])
                *reinterpret_cast<float4*>(op[rr] + 1024 + 16 * lane + 2 * s) =
                    make_float4(a0, a1, b0, b1);
        }
    }
}

extern "C" void kernel_launch(void* const* d_in, const int* in_sizes, int n_in,
                              void* d_out, int out_size, void* d_ws, size_t ws_size,
                              hipStream_t stream) {
    const float* x   = (const float*)d_in[0];
    const float* w1  = (const float*)d_in[1];
    const float* b1  = (const float*)d_in[2];
    const float* g1  = (const float*)d_in[3];
    const float* be1 = (const float*)d_in[4];
    const float* w2  = (const float*)d_in[5];
    const float* b2  = (const float*)d_in[6];
    const float* g2  = (const float*)d_in[7];
    const float* be2 = (const float*)d_in[8];
    const float* fcw = (const float*)d_in[9];
    const float* fcb = (const float*)d_in[10];
    float* out = (float*)d_out;
    int B = in_sizes[0];
    float invB = 1.0f / (float)B;

    float* ws = (float*)d_ws;
    float* p1 = ws;          // 64*32 partials for BN1
    float* p2 = ws + 2048;   // 64*2 partials for BN2

    k_part1<<<64, 256, 0, stream>>>(x, w1, b1, p1, B);
    k_h2f  <<<64, 256, 0, stream>>>(x, w1, b1, p1, w2, b2, g1, be1, p2, B, invB);

    int blocks = (B + 15) / 16;   // 16 rows per block (4 waves x 4 rows)
    k_tree<<<blocks, 256, 0, stream>>>(x, w1, b1, w2, b2, g1, be1, g2, be2,
                                       fcw, fcb, p1, p2, out, B, invB);
}

// Round 3
// 63.504 us; speedup vs baseline: 1.3153x; 1.3153x over previous
//
#include <hip/hip_runtime.h>

#define LEAKY_S 0.01f
#define BN_EPS 1e-5f
#define LOG2E 1.44269504088896340736f

typedef float f32x2 __attribute__((ext_vector_type(2)));
typedef float f32x4 __attribute__((ext_vector_type(4)));

__device__ __forceinline__ float leaky(float v) { return v >= 0.0f ? v : LEAKY_S * v; }
__device__ __forceinline__ float fast_exp2(float v) { return __builtin_amdgcn_exp2f(v); }
// sigmoid(z) with weights pre-scaled by log2e
__device__ __forceinline__ float sig2(float z2) {
    return __builtin_amdgcn_rcpf(1.0f + fast_exp2(-z2));
}
__device__ __forceinline__ void st2(float* p, float a, float b) {
    f32x2 v = {a, b}; *(f32x2*)p = v;
}
__device__ __forceinline__ void st_nt2(float* p, float a, float b) {
    f32x2 v = {a, b}; __builtin_nontemporal_store(v, (f32x2*)p);
}
__device__ __forceinline__ void st_nt4(float* p, float a, float b, float c, float d) {
    f32x4 v = {a, b, c, d}; __builtin_nontemporal_store(v, (f32x4*)p);
}

// ---------------- K1: partial sums (sum, sumsq) of h1 columns over batch ----
__global__ __launch_bounds__(256) void k_part1(const float* __restrict__ x,
        const float* __restrict__ w1, const float* __restrict__ b1,
        float* __restrict__ p1, int B) {
    float w1r[16], b1r[16], s[16], q[16];
#pragma unroll
    for (int j = 0; j < 16; ++j) { w1r[j] = w1[j]; b1r[j] = b1[j]; s[j] = 0.f; q[j] = 0.f; }
    int tid = threadIdx.x;
    int stride = gridDim.x * 256;
    for (int i = blockIdx.x * 256 + tid; i < B; i += stride) {
        float xv = x[i];
#pragma unroll
        for (int j = 0; j < 16; ++j) {
            float h = leaky(fmaf(xv, w1r[j], b1r[j]));
            s[j] += h; q[j] += h * h;
        }
    }
#pragma unroll
    for (int j = 0; j < 16; ++j) {
        for (int off = 32; off >= 1; off >>= 1) {
            s[j] += __shfl_xor(s[j], off, 64);
            q[j] += __shfl_xor(q[j], off, 64);
        }
    }
    __shared__ float red[4][32];
    int w = tid >> 6, lane = tid & 63;
    if (lane == 0) {
#pragma unroll
        for (int j = 0; j < 16; ++j) { red[w][j] = s[j]; red[w][j + 16] = q[j]; }
    }
    __syncthreads();
    if (tid < 32)
        p1[blockIdx.x * 32 + tid] = red[0][tid] + red[1][tid] + red[2][tid] + red[3][tid];
}

// Wave0 helper: fold BN1 + Linear2 into coef[0..15]=a[j], coef[16]=c0.
__device__ __forceinline__ void fold_bn1(const float* __restrict__ p1,
        const float* __restrict__ w2, const float* __restrict__ b2,
        const float* __restrict__ g1, const float* __restrict__ be1,
        float* coef, int tid, float invB) {
    float acc = 0.f;
    for (int i = 0; i < 64; ++i) acc += p1[i * 32 + tid];
    float qacc = __shfl(acc, tid + 16, 64);   // lanes 0..15 fetch sumsq
    float cp = 0.f;
    if (tid < 16) {
        float mean = acc * invB;
        float var  = qacc * invB - mean * mean;
        float inv  = rsqrtf(var + BN_EPS) * g1[tid];
        float sh   = fmaf(-mean, inv, be1[tid]);
        coef[tid] = inv * w2[tid];
        cp = sh * w2[tid];
    }
    for (int off = 8; off >= 1; off >>= 1) cp += __shfl_xor(cp, off, 16);
    if (tid == 0) coef[16] = cp + b2[0];
}

// ---------------- K2: h2 per row + partial (sum,sumsq) for BN2 --------------
__global__ __launch_bounds__(256) void k_h2f(const float* __restrict__ x,
        const float* __restrict__ w1, const float* __restrict__ b1,
        const float* __restrict__ p1, const float* __restrict__ w2,
        const float* __restrict__ b2, const float* __restrict__ g1,
        const float* __restrict__ be1, float* __restrict__ p2, int B, float invB) {
    __shared__ float coef[17];
    int tid = threadIdx.x;
    if (tid < 32) fold_bn1(p1, w2, b2, g1, be1, coef, tid, invB);
    __syncthreads();
    float w1r[16], b1r[16], ar[16];
#pragma unroll
    for (int j = 0; j < 16; ++j) { w1r[j] = w1[j]; b1r[j] = b1[j]; ar[j] = coef[j]; }
    float c0 = coef[16];
    float s = 0.f, q = 0.f;
    int stride = gridDim.x * 256;
    for (int i = blockIdx.x * 256 + tid; i < B; i += stride) {
        float xv = x[i];
        float acc = c0;
#pragma unroll
        for (int j = 0; j < 16; ++j) {
            float h = leaky(fmaf(xv, w1r[j], b1r[j]));
            acc = fmaf(h, ar[j], acc);
        }
        float h2 = leaky(acc);
        s += h2; q += h2 * h2;
    }
    for (int off = 32; off >= 1; off >>= 1) {
        s += __shfl_xor(s, off, 64);
        q += __shfl_xor(q, off, 64);
    }
    __shared__ float red[4][2];
    int w = tid >> 6, lane = tid & 63;
    if (lane == 0) { red[w][0] = s; red[w][1] = q; }
    __syncthreads();
    if (tid == 0) {
        p2[blockIdx.x * 2 + 0] = red[0][0] + red[1][0] + red[2][0] + red[3][0];
        p2[blockIdx.x * 2 + 1] = red[0][1] + red[1][1] + red[2][1] + red[3][1];
    }
}

// ---------------- K3: register tree with INTERLEAVED deep ownership --------
// Lane i owns, at level l>=8, parents {chunk*128 + 2i, 2i+1} so every child
// quad lands at out[... + 4*i]: ALL deep stores are lane-contiguous dwordx4
// (fillBuffer pattern). Parent mus hop lanes via 4 shuffles + 2 selects.
__global__ __launch_bounds__(256) void k_tree(const float* __restrict__ x,
        const float* __restrict__ w1, const float* __restrict__ b1,
        const float* __restrict__ w2, const float* __restrict__ b2,
        const float* __restrict__ g1, const float* __restrict__ be1,
        const float* __restrict__ g2, const float* __restrict__ be2,
        const float* __restrict__ fcw, const float* __restrict__ fcb,
        const float* __restrict__ p1, const float* __restrict__ p2,
        float* __restrict__ out, int B, float invB) {
    __shared__ float wl[1024], bl[1024];
    __shared__ float coef[19];
    __shared__ float x2s[8];
    int tid = threadIdx.x;

    // Stage fc weights (pre-scaled by log2e), swizzled to slot-major so that
    // slot s of level l sits at wl[seg + s*64 + lane], lane-contiguous.
    // Ownership: level 8: lane owns {128+2i+s}; level 9: {256+j2*128+2i+s};
    // level 10: {512+j*128+2i+s}.
    for (int i = tid; i < 1024; i += 256) {
        int d;
        if (i < 128)      d = i;                                   // levels 1..7
        else if (i < 256) { int o = i - 128; d = 128 + ((o & 1) << 6) + (o >> 1); }
        else if (i < 512) { int o = i - 256; d = 256 + ((((o >> 7) << 1) | (o & 1)) << 6) + ((o & 127) >> 1); }
        else              { int o = i - 512; d = 512 + ((((o >> 7) << 1) | (o & 1)) << 6) + ((o & 127) >> 1); }
        wl[d] = fcw[i] * LOG2E;
        bl[d] = fcb[i] * LOG2E;
    }
    if (tid < 32) {
        fold_bn1(p1, w2, b2, g1, be1, coef, tid, invB);
        if (tid == 31) {   // BN2 fold -> s2 (coef[17]), t2 (coef[18])
            float s = 0.f, q = 0.f;
            for (int i = 0; i < 64; ++i) { s += p2[2 * i]; q += p2[2 * i + 1]; }
            float mean = s * invB, var = q * invB - mean * mean;
            float inv = rsqrtf(var + BN_EPS) * g2[0];
            coef[17] = inv;
            coef[18] = fmaf(-mean, inv, be2[0]);
        }
    }
    __syncthreads();
    if (tid < 8) {   // one thread per block-row: recompute h2 -> x2
        int r = blockIdx.x * 8 + tid;
        float xv = (r < B) ? x[r] : 0.f;
        float acc = coef[16];
#pragma unroll
        for (int j = 0; j < 16; ++j) {
            float h = leaky(fmaf(xv, w1[j], b1[j]));
            acc = fmaf(h, coef[j], acc);
        }
        x2s[tid] = fmaf(leaky(acc), coef[17], coef[18]);
    }
    __syncthreads();

    const int w = tid >> 6, lane = tid & 63;
    const int rbase = blockIdx.x * 8 + w * 2;
    float x2[2]; bool act[2]; float* op[2];
#pragma unroll
    for (int rr = 0; rr < 2; ++rr) {
        x2[rr] = x2s[w * 2 + rr];
        act[rr] = (rbase + rr) < B;
        op[rr] = out + (size_t)(rbase + rr) * 2048;
        if (act[rr] && lane == 0) st2(op[rr], 0.f, 1.f);
    }

    float mup[2] = {1.f, 1.f};
    // ---- levels 1..6: shuffle levels ----
#pragma unroll
    for (int l = 1; l <= 6; ++l) {
        const int P = 1 << (l - 1);
        float wv = wl[P + lane], bv = bl[P + lane];
#pragma unroll
        for (int rr = 0; rr < 2; ++rr) {
            float z = fmaf(x2[rr], wv, bv);
            float pz = sig2(z);
            float c0 = mup[rr] * pz, c1 = mup[rr] - c0;
            if (act[rr] && lane < P) {
                if (l >= 5) st_nt2(op[rr] + 2 * (P + lane), c0, c1);
                else        st2(op[rr] + 2 * (P + lane), c0, c1);
            }
            float s0 = __shfl(c0, lane >> 1, 64);
            float s1 = __shfl(c1, lane >> 1, 64);
            mup[rr] = (lane & 1) ? s1 : s0;
        }
    }
    // ---- level 7: parent 64+lane, children stay in-lane ----
    float c2[2][2];
    {
        float wv = wl[64 + lane], bv = bl[64 + lane];
#pragma unroll
        for (int rr = 0; rr < 2; ++rr) {
            float z = fmaf(x2[rr], wv, bv);
            float pz = sig2(z);
            c2[rr][0] = mup[rr] * pz;
            c2[rr][1] = mup[rr] - c2[rr][0];
            if (act[rr]) st_nt2(op[rr] + 128 + 2 * lane, c2[rr][0], c2[rr][1]);
        }
    }
    // ---- level 8: parents {128+2i, 128+2i+1}; mus in-lane (c2) ----
    float c4[2][4];
#pragma unroll
    for (int s = 0; s < 2; ++s) {
        float wv = wl[128 + (s << 6) + lane], bv = bl[128 + (s << 6) + lane];
#pragma unroll
        for (int rr = 0; rr < 2; ++rr) {
            float z = fmaf(x2[rr], wv, bv);
            float pz = sig2(z);
            c4[rr][2 * s]     = c2[rr][s] * pz;
            c4[rr][2 * s + 1] = c2[rr][s] - c4[rr][2 * s];
        }
    }
#pragma unroll
    for (int rr = 0; rr < 2; ++rr)
        if (act[rr])
            st_nt4(op[rr] + 256 + (lane << 2), c4[rr][0], c4[rr][1], c4[rr][2], c4[rr][3]);
    // ---- level 9: parents {256 + j2*128 + 2i + s}; mus from lane j2*32+(i>>1)
    float c8[2][2][4];
#pragma unroll
    for (int j2 = 0; j2 < 2; ++j2) {
        int src = (j2 << 5) + (lane >> 1);
        float wv0 = wl[256 + ((2 * j2) << 6) + lane],     bv0 = bl[256 + ((2 * j2) << 6) + lane];
        float wv1 = wl[256 + ((2 * j2 + 1) << 6) + lane], bv1 = bl[256 + ((2 * j2 + 1) << 6) + lane];
#pragma unroll
        for (int rr = 0; rr < 2; ++rr) {
            float A  = __shfl(c4[rr][0], src, 64);
            float Bv = __shfl(c4[rr][1], src, 64);
            float C  = __shfl(c4[rr][2], src, 64);
            float D  = __shfl(c4[rr][3], src, 64);
            float m0 = (lane & 1) ? C : A;    // mu of parent (j2, s=0)
            float m1 = (lane & 1) ? D : Bv;   // mu of parent (j2, s=1)
            float z0 = fmaf(x2[rr], wv0, bv0);
            float z1 = fmaf(x2[rr], wv1, bv1);
            float p0 = sig2(z0), p1v = sig2(z1);
            c8[rr][j2][0] = m0 * p0;
            c8[rr][j2][1] = m0 - c8[rr][j2][0];
            c8[rr][j2][2] = m1 * p1v;
            c8[rr][j2][3] = m1 - c8[rr][j2][2];
            if (act[rr])
                st_nt4(op[rr] + 512 + (j2 << 8) + (lane << 2),
                       c8[rr][j2][0], c8[rr][j2][1], c8[rr][j2][2], c8[rr][j2][3]);
        }
    }
    // ---- level 10: parents {512 + j*128 + 2i + s}; mus from lane (j&1)*32+(i>>1)
#pragma unroll
    for (int j = 0; j < 4; ++j) {
        const int j2 = j >> 1;
        int src = ((j & 1) << 5) + (lane >> 1);
        float wv0 = wl[512 + ((2 * j) << 6) + lane],     bv0 = bl[512 + ((2 * j) << 6) + lane];
        float wv1 = wl[512 + ((2 * j + 1) << 6) + lane], bv1 = bl[512 + ((2 * j + 1) << 6) + lane];
#pragma unroll
        for (int rr = 0; rr < 2; ++rr) {
            float A  = __shfl(c8[rr][j2][0], src, 64);
            float Bv = __shfl(c8[rr][j2][1], src, 64);
            float C  = __shfl(c8[rr][j2][2], src, 64);
            float D  = __shfl(c8[rr][j2][3], src, 64);
            float m0 = (lane & 1) ? C : A;    // mu of parent (j, s=0)
            float m1 = (lane & 1) ? D : Bv;   // mu of parent (j, s=1)
            float z0 = fmaf(x2[rr], wv0, bv0);
            float z1 = fmaf(x2[rr], wv1, bv1);
            float p0 = sig2(z0), p1v = sig2(z1);
            float a0 = m0 * p0,  a1 = m0 - a0;
            float b0 = m1 * p1v, b1 = m1 - b0;
            if (act[rr])
                st_nt4(op[rr] + 1024 + (j << 8) + (lane << 2), a0, a1, b0, b1);
        }
    }
}

extern "C" void kernel_launch(void* const* d_in, const int* in_sizes, int n_in,
                              void* d_out, int out_size, void* d_ws, size_t ws_size,
                              hipStream_t stream) {
    const float* x   = (const float*)d_in[0];
    const float* w1  = (const float*)d_in[1];
    const float* b1  = (const float*)d_in[2];
    const float* g1  = (const float*)d_in[3];
    const float* be1 = (const float*)d_in[4];
    const float* w2  = (const float*)d_in[5];
    const float* b2  = (const float*)d_in[6];
    const float* g2  = (const float*)d_in[7];
    const float* be2 = (const float*)d_in[8];
    const float* fcw = (const float*)d_in[9];
    const float* fcb = (const float*)d_in[10];
    float* out = (float*)d_out;
    int B = in_sizes[0];
    float invB = 1.0f / (float)B;

    float* ws = (float*)d_ws;
    float* p1 = ws;          // 64*32 partials for BN1
    float* p2 = ws + 2048;   // 64*2 partials for BN2

    k_part1<<<64, 256, 0, stream>>>(x, w1, b1, p1, B);
    k_h2f  <<<64, 256, 0, stream>>>(x, w1, b1, p1, w2, b2, g1, be1, p2, B, invB);

    int blocks = (B + 7) / 8;   // 8 rows per block (4 waves x 2 rows)
    k_tree<<<blocks, 256, 0, stream>>>(x, w1, b1, w2, b2, g1, be1, g2, be2,
                                       fcw, fcb, p1, p2, out, B, invB);
}